// Round 14
// baseline (49.529 us; speedup 1.0000x reference)
//
#include <hip/hip_runtime.h>

#define N_NODES   100000
#define N_EDGES   1600000
#define N_GRAPHS  256
#define D         32
#define GD        (N_GRAPHS * D)   // 8192
#define LSTRIDE   257              // lds[d*257+g]: banks (4c+j+g)%32 spread
#define NBLK      256              // 1 block/CU, 16 waves
#define SCALE_F   1048576.0f       // 2^20 fixed-point scale
#define INV_SCALE 9.5367431640625e-07f

typedef float f32x4 __attribute__((ext_vector_type(4)));

// ---------- edge aggregation: depth-3 triple-stream pipeline, plain loads ----------
// R13 (depth-2, 46.8 us) with one variable changed: 3 stride-streams per
// thread (units i0+k*3S, +S, +2S). Iter k issues: src for trio k+2,
// batch+ea4 for trio k+1, then 12 LDS adds for trio k. 3x16B in flight
// per lane; branch-free tail (index clamp + value mask).
__global__ __launch_bounds__(1024) void edge_stream_kernel(
        const float* __restrict__ ea,
        const int* __restrict__ src,
        const int* __restrict__ batch,
        int* __restrict__ epart /* [NBLK][GD], (g,d)-major */) {
    __shared__ int lds[D * LSTRIDE];               // 32.9 KB
    for (int i = threadIdx.x; i < D * LSTRIDE; i += 1024) lds[i] = 0;
    __syncthreads();

    const f32x4* __restrict__ ea4 = (const f32x4*)ea;
    const int total = N_EDGES * (D / 4);           // 12.8M float4 units
    const int S     = NBLK * 1024;                 // 262144
    const int S3    = 3 * S;
    const int i0    = blockIdx.x * 1024 + threadIdx.x;
    const int NIT   = (total + S3 - 1) / S3;       // 17
    const int cbase = ((i0 & 7) * 4) * LSTRIDE;    // c invariant (S % 8 == 0)

    // ---- prologue: fill trio 0 (ready) and trio-1 src ----
    int iA = i0, iB = i0 + S, iC = i0 + 2 * S;
    f32x4 v0, v1, v2;
    int g0, g1, g2, s0n, s1n, s2n;
    {
        const int sA = src[min(iA, total - 1) >> 3];
        const int sB = src[min(iB, total - 1) >> 3];
        const int sC = src[min(iC, total - 1) >> 3];
        g0 = batch[sA];
        g1 = batch[sB];
        g2 = batch[sC];
        const f32x4 t0 = ea4[min(iA, total - 1)];
        const f32x4 t1 = ea4[min(iB, total - 1)];
        const f32x4 t2 = ea4[min(iC, total - 1)];
        v0 = t0 * ((iA < total) ? 1.f : 0.f);
        v1 = t1 * ((iB < total) ? 1.f : 0.f);
        v2 = t2 * ((iC < total) ? 1.f : 0.f);
        s0n = src[min(iA + S3, total - 1) >> 3];
        s1n = src[min(iB + S3, total - 1) >> 3];
        s2n = src[min(iC + S3, total - 1) >> 3];
    }

    for (int k = 0; k < NIT; ++k) {
        const int iA2 = iA + S3, iB2 = iB + S3, iC2 = iC + S3;   // trio k+1
        // issue: src for trio k+2
        const int s0nn = src[min(iA2 + S3, total - 1) >> 3];
        const int s1nn = src[min(iB2 + S3, total - 1) >> 3];
        const int s2nn = src[min(iC2 + S3, total - 1) >> 3];
        // issue: batch + ea4 for trio k+1
        const int g0n = batch[s0n];
        const int g1n = batch[s1n];
        const int g2n = batch[s2n];
        const f32x4 t0 = ea4[min(iA2, total - 1)];
        const f32x4 t1 = ea4[min(iB2, total - 1)];
        const f32x4 t2 = ea4[min(iC2, total - 1)];
        const f32x4 v0n = t0 * ((iA2 < total) ? 1.f : 0.f);
        const f32x4 v1n = t1 * ((iB2 < total) ? 1.f : 0.f);
        const f32x4 v2n = t2 * ((iC2 < total) ? 1.f : 0.f);

        // LDS adds for trio k
        const int b0 = cbase + g0;
        atomicAdd(&lds[b0              ], __float2int_rn(v0.x * SCALE_F));
        atomicAdd(&lds[b0 +     LSTRIDE], __float2int_rn(v0.y * SCALE_F));
        atomicAdd(&lds[b0 + 2 * LSTRIDE], __float2int_rn(v0.z * SCALE_F));
        atomicAdd(&lds[b0 + 3 * LSTRIDE], __float2int_rn(v0.w * SCALE_F));
        const int b1 = cbase + g1;
        atomicAdd(&lds[b1              ], __float2int_rn(v1.x * SCALE_F));
        atomicAdd(&lds[b1 +     LSTRIDE], __float2int_rn(v1.y * SCALE_F));
        atomicAdd(&lds[b1 + 2 * LSTRIDE], __float2int_rn(v1.z * SCALE_F));
        atomicAdd(&lds[b1 + 3 * LSTRIDE], __float2int_rn(v1.w * SCALE_F));
        const int b2 = cbase + g2;
        atomicAdd(&lds[b2              ], __float2int_rn(v2.x * SCALE_F));
        atomicAdd(&lds[b2 +     LSTRIDE], __float2int_rn(v2.y * SCALE_F));
        atomicAdd(&lds[b2 + 2 * LSTRIDE], __float2int_rn(v2.z * SCALE_F));
        atomicAdd(&lds[b2 + 3 * LSTRIDE], __float2int_rn(v2.w * SCALE_F));

        iA = iA2; iB = iB2; iC = iC2;
        v0 = v0n; v1 = v1n; v2 = v2n;
        g0 = g0n; g1 = g1n; g2 = g2n;
        s0n = s0nn; s1n = s1nn; s2n = s2nn;
    }
    __syncthreads();

    int* __restrict__ my = epart + (size_t)blockIdx.x * GD;
    for (int j = threadIdx.x; j < GD; j += 1024)
        my[j] = lds[(j & 31) * LSTRIDE + (j >> 5)];   // coalesced, ≤2-way bank
}

// ---------- finish: node-range sum + epart column-sum + MLP, one block per graph ----------
__global__ __launch_bounds__(1024) void finish_kernel(
        const float* __restrict__ x,
        const int* __restrict__ batch,
        const int* __restrict__ epart,    // [NBLK][GD]
        const float* __restrict__ u,
        const float* __restrict__ W,      // [3D][D]
        const float* __restrict__ bias,
        float* __restrict__ out) {
    const int g = blockIdx.x;
    __shared__ float  Ws[3 * D * D];               // 12 KB
    __shared__ float4 red[1024];                   // 16 KB
    __shared__ int4   ered[128][9];                // 18.4 KB (pad col -> bank spread)
    __shared__ float  accN[D], accE[D], ush[D];

    for (int j = threadIdx.x; j < 3 * D * D; j += 1024) Ws[j] = W[j];
    if (threadIdx.x < D) ush[threadIdx.x] = u[g * D + threadIdx.x];

    // node range of graph g (batch sorted)
    int lo = 0, hi = N_NODES;
    while (lo < hi) { const int m = (lo + hi) >> 1; if (batch[m] < g) lo = m + 1; else hi = m; }
    const int r0 = lo;
    hi = N_NODES;
    while (lo < hi) { const int m = (lo + hi) >> 1; if (batch[m] < g + 1) lo = m + 1; else hi = m; }
    const int r1 = lo;

    // ---- node sum: 128 row slots x 8 float4 cols (~3 rows each) ----
    {
        const int s = threadIdx.x >> 3;
        const int c = threadIdx.x & 7;
        const float4* __restrict__ x4 = (const float4*)x;
        float4 a = make_float4(0.f, 0.f, 0.f, 0.f);
        for (int r = r0 + s; r < r1; r += 128) {
            const float4 v = x4[r * 8 + c];
            a.x += v.x; a.y += v.y; a.z += v.z; a.w += v.w;
        }
        red[threadIdx.x] = a;
    }

    // ---- epart partial: 128 p-groups x 8 int4 cols, 2 loads each ----
    {
        const int pg = threadIdx.x >> 3;
        const int q  = threadIdx.x & 7;
        const int4* __restrict__ ep4 = (const int4*)epart + (size_t)g * 8 + q;
        int4 s4 = ep4[(size_t)pg * (GD / 4)];
        const int4 t4 = ep4[(size_t)(pg + 128) * (GD / 4)];
        s4.x += t4.x; s4.y += t4.y; s4.z += t4.z; s4.w += t4.w;
        ered[pg][q] = s4;
    }
    __syncthreads();

    // ---- stage 2: red 1024->256, ered 128->32 (disjoint thread ranges) ----
    if (threadIdx.x < 256) {
        float4 t = red[threadIdx.x];
        const float4 b1 = red[threadIdx.x + 256];
        const float4 b2 = red[threadIdx.x + 512];
        const float4 b3 = red[threadIdx.x + 768];
        t.x += b1.x + b2.x + b3.x; t.y += b1.y + b2.y + b3.y;
        t.z += b1.z + b2.z + b3.z; t.w += b1.w + b2.w + b3.w;
        red[threadIdx.x] = t;
    } else if (threadIdx.x < 512) {
        const int t2 = threadIdx.x - 256;
        const int j = t2 >> 3, q = t2 & 7;         // j 0..31
        int4 s4 = ered[j][q];
        const int4 a1 = ered[j + 32][q];
        const int4 a2 = ered[j + 64][q];
        const int4 a3 = ered[j + 96][q];
        s4.x += a1.x + a2.x + a3.x; s4.y += a1.y + a2.y + a3.y;
        s4.z += a1.z + a2.z + a3.z; s4.w += a1.w + a2.w + a3.w;
        ered[j][q] = s4;
    }
    __syncthreads();

    // ---- stage 3: 32 slots -> final vectors ----
    if (threadIdx.x < 8) {                         // accN
        float4 t = make_float4(0.f, 0.f, 0.f, 0.f);
        #pragma unroll
        for (int s2 = 0; s2 < 32; ++s2) {
            const float4 b = red[s2 * 8 + threadIdx.x];
            t.x += b.x; t.y += b.y; t.z += b.z; t.w += b.w;
        }
        ((float4*)accN)[threadIdx.x] = t;
    } else if (threadIdx.x < 16) {                 // accE
        const int q = threadIdx.x - 8;
        int4 s4 = make_int4(0, 0, 0, 0);
        #pragma unroll
        for (int j = 0; j < 32; ++j) {
            const int4 b = ered[j][q];
            s4.x += b.x; s4.y += b.y; s4.z += b.z; s4.w += b.w;
        }
        accE[q * 4 + 0] = (float)s4.x * INV_SCALE;
        accE[q * 4 + 1] = (float)s4.y * INV_SCALE;
        accE[q * 4 + 2] = (float)s4.z * INV_SCALE;
        accE[q * 4 + 3] = (float)s4.w * INV_SCALE;
    }
    __syncthreads();

    if (threadIdx.x < D) {
        const int d = threadIdx.x;
        float sacc = bias[d];
        #pragma unroll
        for (int kk = 0; kk < D; ++kk) sacc += accN[kk] * Ws[kk * D + d];
        #pragma unroll
        for (int kk = 0; kk < D; ++kk) sacc += accE[kk] * Ws[(D + kk) * D + d];
        #pragma unroll
        for (int kk = 0; kk < D; ++kk) sacc += ush[kk] * Ws[(2 * D + kk) * D + d];
        out[g * D + d] = fmaxf(sacc, 0.f);
    }
}

extern "C" void kernel_launch(void* const* d_in, const int* in_sizes, int n_in,
                              void* d_out, int out_size, void* d_ws, size_t ws_size,
                              hipStream_t stream) {
    const float* x     = (const float*)d_in[0];
    const int*   ei    = (const int*)  d_in[1];    // [2][N_EDGES]; row 0 = src
    const float* ea    = (const float*)d_in[2];
    const float* u     = (const float*)d_in[3];
    const int*   batch = (const int*)  d_in[4];
    const float* W     = (const float*)d_in[5];
    const float* bias  = (const float*)d_in[6];
    float*       out   = (float*)d_out;

    int* epart = (int*)d_ws;                       // [NBLK][GD] i32 = 8 MB

    edge_stream_kernel<<<NBLK, 1024, 0, stream>>>(ea, ei, batch, epart);
    finish_kernel     <<<N_GRAPHS, 1024, 0, stream>>>(x, batch, epart, u, W, bias, out);
}

// Round 15
// 43.599 us; speedup vs baseline: 1.1360x; 1.1360x over previous
//
#include <hip/hip_runtime.h>

#define N_NODES   100000
#define N_EDGES   1600000
#define N_GRAPHS  256
#define D         32
#define GD        (N_GRAPHS * D)   // 8192
#define LSTRIDE   257              // lds[d*257+g]: banks (4c+j+g)%32 spread
#define NBLK      256              // edge blocks (1/CU, 16 waves)
#define SCALE_F   1048576.0f       // 2^20 fixed-point scale
#define INV_SCALE 9.5367431640625e-07f

typedef float f32x4 __attribute__((ext_vector_type(4)));

// ---------- fused: blocks [0,NBLK) = R13 edge depth-2 pipeline (verified 46.8);
// ----------        blocks [NBLK,NBLK+256) = node partial for graph (bid-NBLK) ----------
__global__ __launch_bounds__(1024) void edge_node_kernel(
        const float* __restrict__ ea,
        const int* __restrict__ src,
        const int* __restrict__ batch,
        const float* __restrict__ x,
        int* __restrict__ epart /* [NBLK][GD], (g,d)-major */,
        float* __restrict__ npart /* [256][32] */) {
    __shared__ int lds[D * LSTRIDE];               // 32.9 KB (node path reuses as float4[1024])

    if (blockIdx.x >= NBLK) {
        // ---- node partial for graph g (R7-verified path) ----
        const int g = blockIdx.x - NBLK;
        float4* red = (float4*)lds;                // 16 KB of the 32.9
        int lo = 0, hi = N_NODES;
        while (lo < hi) { const int m = (lo + hi) >> 1; if (batch[m] < g) lo = m + 1; else hi = m; }
        const int r0 = lo;
        hi = N_NODES;
        while (lo < hi) { const int m = (lo + hi) >> 1; if (batch[m] < g + 1) lo = m + 1; else hi = m; }
        const int r1 = lo;

        const int s = threadIdx.x >> 3;            // 0..127 row slots
        const int c = threadIdx.x & 7;             // float4 column
        const float4* __restrict__ x4 = (const float4*)x;

        float4 a = make_float4(0.f, 0.f, 0.f, 0.f);
        for (int r = r0 + s; r < r1; r += 128) {
            const float4 v = x4[r * 8 + c];
            a.x += v.x; a.y += v.y; a.z += v.z; a.w += v.w;
        }
        red[threadIdx.x] = a;
        __syncthreads();
        if (threadIdx.x < 256) {
            float4 t = red[threadIdx.x];
            const float4 b1 = red[threadIdx.x + 256];
            const float4 b2 = red[threadIdx.x + 512];
            const float4 b3 = red[threadIdx.x + 768];
            t.x += b1.x + b2.x + b3.x; t.y += b1.y + b2.y + b3.y;
            t.z += b1.z + b2.z + b3.z; t.w += b1.w + b2.w + b3.w;
            red[threadIdx.x] = t;
        }
        __syncthreads();
        if (threadIdx.x < 8) {
            float4 t = make_float4(0.f, 0.f, 0.f, 0.f);
            #pragma unroll
            for (int s2 = 0; s2 < 32; ++s2) {
                const float4 b = red[s2 * 8 + threadIdx.x];
                t.x += b.x; t.y += b.y; t.z += b.z; t.w += b.w;
            }
            ((float4*)(npart + (size_t)g * D))[threadIdx.x] = t;
        }
        return;
    }

    // ---- edge path: depth-2 pair pipeline (R13, unchanged) ----
    for (int i = threadIdx.x; i < D * LSTRIDE; i += 1024) lds[i] = 0;
    __syncthreads();

    const f32x4* __restrict__ ea4 = (const f32x4*)ea;
    const int total = N_EDGES * (D / 4);           // 12.8M float4 units
    const int S     = NBLK * 1024;                 // 262144
    const int S2    = 2 * S;
    const int i0    = blockIdx.x * 1024 + threadIdx.x;
    const int NIT   = (total + S2 - 1) / S2;       // 25
    const int cbase = ((i0 & 7) * 4) * LSTRIDE;    // c invariant (S % 8 == 0)

    int iA = i0, iB = i0 + S;
    f32x4 v0, v1;
    int g0, g1, s0n, s1n;
    {
        const int sA = src[min(iA, total - 1) >> 3];
        const int sB = src[min(iB, total - 1) >> 3];
        g0 = batch[sA];
        g1 = batch[sB];
        const f32x4 t0 = ea4[min(iA, total - 1)];
        const f32x4 t1 = ea4[min(iB, total - 1)];
        v0 = t0 * ((iA < total) ? 1.f : 0.f);
        v1 = t1 * ((iB < total) ? 1.f : 0.f);
        s0n = src[min(iA + S2, total - 1) >> 3];
        s1n = src[min(iB + S2, total - 1) >> 3];
    }

    for (int k = 0; k < NIT; ++k) {
        const int iA2 = iA + S2, iB2 = iB + S2;    // pair k+1
        const int s0nn = src[min(iA2 + S2, total - 1) >> 3];
        const int s1nn = src[min(iB2 + S2, total - 1) >> 3];
        const int g0n = batch[s0n];
        const int g1n = batch[s1n];
        const f32x4 t0 = ea4[min(iA2, total - 1)];
        const f32x4 t1 = ea4[min(iB2, total - 1)];
        const f32x4 v0n = t0 * ((iA2 < total) ? 1.f : 0.f);
        const f32x4 v1n = t1 * ((iB2 < total) ? 1.f : 0.f);

        const int b0 = cbase + g0;
        atomicAdd(&lds[b0              ], __float2int_rn(v0.x * SCALE_F));
        atomicAdd(&lds[b0 +     LSTRIDE], __float2int_rn(v0.y * SCALE_F));
        atomicAdd(&lds[b0 + 2 * LSTRIDE], __float2int_rn(v0.z * SCALE_F));
        atomicAdd(&lds[b0 + 3 * LSTRIDE], __float2int_rn(v0.w * SCALE_F));
        const int b1 = cbase + g1;
        atomicAdd(&lds[b1              ], __float2int_rn(v1.x * SCALE_F));
        atomicAdd(&lds[b1 +     LSTRIDE], __float2int_rn(v1.y * SCALE_F));
        atomicAdd(&lds[b1 + 2 * LSTRIDE], __float2int_rn(v1.z * SCALE_F));
        atomicAdd(&lds[b1 + 3 * LSTRIDE], __float2int_rn(v1.w * SCALE_F));

        iA = iA2; iB = iB2;
        v0 = v0n; v1 = v1n; g0 = g0n; g1 = g1n; s0n = s0nn; s1n = s1nn;
    }
    __syncthreads();

    int* __restrict__ my = epart + (size_t)blockIdx.x * GD;
    for (int j = threadIdx.x; j < GD; j += 1024)
        my[j] = lds[(j & 31) * LSTRIDE + (j >> 5)];   // coalesced, ≤2-way bank
}

// ---------- finish: epart column-sum (int4) + npart + MLP, one block per graph ----------
__global__ __launch_bounds__(1024) void finish_kernel(
        const float* __restrict__ npart,  // [256][32]
        const int* __restrict__ epart,    // [NBLK][GD]
        const float* __restrict__ u,
        const float* __restrict__ W,      // [3D][D]
        const float* __restrict__ bias,
        float* __restrict__ out) {
    const int g = blockIdx.x;
    __shared__ float Ws[3 * D * D];                // 12 KB
    __shared__ int4  ered[128][9];                 // 18.4 KB (pad col -> bank spread)
    __shared__ float accN[D], accE[D], ush[D];

    for (int j = threadIdx.x; j < 3 * D * D; j += 1024) Ws[j] = W[j];
    if (threadIdx.x < D) {
        ush [threadIdx.x] = u[g * D + threadIdx.x];
        accN[threadIdx.x] = npart[g * D + threadIdx.x];
    }

    // ---- epart partial: 128 p-groups x 8 int4 cols, 2 loads each ----
    {
        const int pg = threadIdx.x >> 3;
        const int q  = threadIdx.x & 7;
        const int4* __restrict__ ep4 = (const int4*)epart + (size_t)g * 8 + q;
        int4 s4 = ep4[(size_t)pg * (GD / 4)];
        const int4 t4 = ep4[(size_t)(pg + 128) * (GD / 4)];
        s4.x += t4.x; s4.y += t4.y; s4.z += t4.z; s4.w += t4.w;
        ered[pg][q] = s4;
    }
    __syncthreads();

    // ---- stage 2: ered 128 -> 32 ----
    if (threadIdx.x < 256) {
        const int j = threadIdx.x >> 3, q = threadIdx.x & 7;   // j 0..31
        int4 s4 = ered[j][q];
        const int4 a1 = ered[j + 32][q];
        const int4 a2 = ered[j + 64][q];
        const int4 a3 = ered[j + 96][q];
        s4.x += a1.x + a2.x + a3.x; s4.y += a1.y + a2.y + a3.y;
        s4.z += a1.z + a2.z + a3.z; s4.w += a1.w + a2.w + a3.w;
        ered[j][q] = s4;
    }
    __syncthreads();

    // ---- stage 3: 32 -> accE ----
    if (threadIdx.x < 8) {
        const int q = threadIdx.x;
        int4 s4 = make_int4(0, 0, 0, 0);
        #pragma unroll
        for (int j = 0; j < 32; ++j) {
            const int4 b = ered[j][q];
            s4.x += b.x; s4.y += b.y; s4.z += b.z; s4.w += b.w;
        }
        accE[q * 4 + 0] = (float)s4.x * INV_SCALE;
        accE[q * 4 + 1] = (float)s4.y * INV_SCALE;
        accE[q * 4 + 2] = (float)s4.z * INV_SCALE;
        accE[q * 4 + 3] = (float)s4.w * INV_SCALE;
    }
    __syncthreads();

    if (threadIdx.x < D) {
        const int d = threadIdx.x;
        float sacc = bias[d];
        #pragma unroll
        for (int kk = 0; kk < D; ++kk) sacc += accN[kk] * Ws[kk * D + d];
        #pragma unroll
        for (int kk = 0; kk < D; ++kk) sacc += accE[kk] * Ws[(D + kk) * D + d];
        #pragma unroll
        for (int kk = 0; kk < D; ++kk) sacc += ush[kk] * Ws[(2 * D + kk) * D + d];
        out[g * D + d] = fmaxf(sacc, 0.f);
    }
}

extern "C" void kernel_launch(void* const* d_in, const int* in_sizes, int n_in,
                              void* d_out, int out_size, void* d_ws, size_t ws_size,
                              hipStream_t stream) {
    const float* x     = (const float*)d_in[0];
    const int*   ei    = (const int*)  d_in[1];    // [2][N_EDGES]; row 0 = src
    const float* ea    = (const float*)d_in[2];
    const float* u     = (const float*)d_in[3];
    const int*   batch = (const int*)  d_in[4];
    const float* W     = (const float*)d_in[5];
    const float* bias  = (const float*)d_in[6];
    float*       out   = (float*)d_out;

    // ws: [npart GD f32 = 32KB][epart NBLK*GD i32 = 8MB]
    float* npart = (float*)d_ws;
    int*   epart = (int*)(npart + GD);

    edge_node_kernel<<<NBLK + N_GRAPHS, 1024, 0, stream>>>(ea, ei, batch, x, epart, npart);
    finish_kernel   <<<N_GRAPHS, 1024, 0, stream>>>(npart, epart, u, W, bias, out);
}